// Round 4
// baseline (201.154 us; speedup 1.0000x reference)
//
#include <hip/hip_runtime.h>
#include <math.h>

// CTC batch cost (Keras ctc_batch_cost), gfx950. B=256,T=512,V=256,L=64,S=129.
//
// One wave = one batch element. Lane L owns extended states 2L (blank) and
// 2L+1 (label L); lane 63 also owns s=128 privately.
//
// Scaled forward DP in linear space with PER-LANE power-of-two rescaling:
//   stored a * 2^C == true alpha;  C integer-valued float, per lane.
//   incoming pa1 (prev lane's a1 via DPP wave_shr:1) is converted between
//   scales with f = 2^(C[l-1]-C[l]) (exponent-bit arithmetic, exact).
// Frontier handling: dead lanes (all-zero alphas) adopt the left neighbor's
// C at each rescale; the reachability frontier advances exactly 1 lane per
// step, so phase A (t<128, until all lanes are live) rescales EVERY step;
// phase B rescales every 8 steps. No transcendentals anywhere in the loop.
//
// Memory: no LDS at all. Per step a lane consumes 2 floats: blank prob
// (wave-uniform address -> scalar-load path) and its label prob (per-lane
// gather). Loaded directly global->VGPR in 32-step double-buffered chunks.

#define BB   256
#define TI   512
#define VV   256
#define LL   64
#define CH   32
#define NCH  (TI / CH)          // 16 chunks
#define EPSF 1e-7f
#define LN2F 0.6931471805599453f

#if __has_builtin(__builtin_amdgcn_logf)
__device__ __forceinline__ float flog2(float x) { return __builtin_amdgcn_logf(x); }
#else
__device__ __forceinline__ float flog2(float x) { return __log2f(x); }
#endif

template <int CTRL>
__device__ __forceinline__ float dppf(float oldv, float v) {
    return __int_as_float(__builtin_amdgcn_update_dpp(
        __float_as_int(oldv), __float_as_int(v), CTRL, 0xF, 0xF, false));
}
// lane i <- lane i-1; lane 0 <- 0.0f  (v_mov_b32_dpp wave_shr:1)
__device__ __forceinline__ float shup0(float x) { return dppf<0x138>(0.0f, x); }

struct DP {
    float a0, a1, a128;   // scaled alphas (a128 meaningful on lane 63)
    float C;              // log2 of this lane's scale (integer-valued float)
    float f, fs;          // 2^(C[l-1]-C[l]), and f*skip
    float skipf;
    int   lane;
};

__device__ __forceinline__ void rescale(DP& d) {
    float m  = fmaxf(fmaxf(d.a0, d.a1), d.a128);     // v_max3
    int   mi    = __float_as_int(m);                 // m >= 0
    int   ebits = mi & 0x7f800000;
    bool  dead  = (ebits == 0);                      // m < 2^-126 (0/denorm)
    float s = __int_as_float((254 << 23) - ebits);   // exact 2^-E
    s = dead ? 1.0f : s;
    d.a0 *= s; d.a1 *= s; d.a128 *= s;               // exact pow2 scaling
    float Ei  = (float)((mi >> 23) - 127);           // E (unused if dead)
    float Cm1 = shup0(d.C);                          // left C (pre-update)
    d.C = dead ? Cm1 : (d.C + Ei);                   // dead lanes adopt
    float Cm1b = shup0(d.C);                         // left C (post-update)
    int dCi = (int)(Cm1b - d.C);                     // exact integer
    int e = dCi + 127;
    e = e < 0 ? 0 : (e > 254 ? 254 : e);             // clamp: f=0 / f=2^127
    float fn = __int_as_float(e << 23);              // 2^dCi
    d.f  = (d.lane == 0) ? 0.0f : fn;                // alpha[-1] == 0
    d.fs = d.f * d.skipf;
}

__device__ __forceinline__ void dp_step(DP& d, float pb, float pl) {
    float pa1 = shup0(d.a1);                         // alpha[2L-1], prev scale
    float s01 = d.a0 + d.a1;
    float na0   = fmaf(pa1, d.f,  d.a0) * pb;        // (a0 + pa1*f)*pb
    float na1   = fmaf(pa1, d.fs, s01)  * pl;        // (a1+a0+skip*pa1*f)*pl
    float na128 = (d.a128 + d.a1) * pb;              // lane 63
    d.a0 = na0; d.a1 = na1; d.a128 = na128;
}

template <bool PA, bool FIRST>
__device__ __forceinline__ void dp_chunk(DP& d, const float (&pb)[CH],
                                         const float (&pl)[CH]) {
    #pragma unroll
    for (int tt = 0; tt < CH; ++tt) {
        if (FIRST && tt == 0) {
            d.a0 = (d.lane == 0) ? pb[0] : 0.0f;     // alpha0: s=0, s=1 only
            d.a1 = (d.lane == 0) ? pl[0] : 0.0f;
        } else {
            dp_step(d, pb[tt], pl[tt]);
        }
        if (PA || (tt & 7) == 7) rescale(d);
    }
}

__device__ __forceinline__ void load_chunk(const float* pbase, const float* lbase,
                                           int c, float (&pb)[CH], float (&pl)[CH]) {
    const float* pp = pbase + c * CH * VV;
    const float* ll = lbase + c * CH * VV;
    #pragma unroll
    for (int i = 0; i < CH; ++i) {
        pb[i] = pp[i * VV] + EPSF;                   // wave-uniform (blank col)
        pl[i] = ll[i * VV] + EPSF;                   // per-lane gather
    }
}

__global__ __launch_bounds__(64) void ctc_kernel(
        const int* __restrict__ y_true,
        const float* __restrict__ y_pred,
        float* __restrict__ out) {
    const int b    = blockIdx.x;
    const int lane = threadIdx.x;
    const float* src = y_pred + (size_t)b * TI * VV;

    const int myLab   = y_true[b * LL + lane];
    const int prevLab = __shfl_up(myLab, 1);

    DP d;
    d.lane  = lane;
    d.skipf = (lane == 0 || myLab != prevLab) ? 1.0f : 0.0f;
    d.a0 = 0.0f; d.a1 = 0.0f; d.a128 = 0.0f;
    d.C = 0.0f; d.f = 0.0f; d.fs = 0.0f;

    const float* pbase = src + (VV - 1);
    const float* lbase = src + myLab;

    float b0p[CH], b0l[CH], b1p[CH], b1l[CH];

    // phase A: chunks 0..3 (t < 128), per-step rescale (frontier active)
    load_chunk(pbase, lbase, 0, b0p, b0l);
    load_chunk(pbase, lbase, 1, b1p, b1l);
    dp_chunk<true, true >(d, b0p, b0l);              // chunk 0
    load_chunk(pbase, lbase, 2, b0p, b0l);
    dp_chunk<true, false>(d, b1p, b1l);              // chunk 1
    load_chunk(pbase, lbase, 3, b1p, b1l);
    dp_chunk<true, false>(d, b0p, b0l);              // chunk 2
    load_chunk(pbase, lbase, 4, b0p, b0l);
    dp_chunk<true, false>(d, b1p, b1l);              // chunk 3

    // phase B: chunks 4..15, all lanes live, rescale every 8 steps
    for (int c = 4; c < NCH; c += 2) {
        load_chunk(pbase, lbase, c + 1, b1p, b1l);
        dp_chunk<false, false>(d, b0p, b0l);
        if (c + 2 < NCH) load_chunk(pbase, lbase, c + 2, b0p, b0l);
        dp_chunk<false, false>(d, b1p, b1l);
    }

    // loss = -ln2 * (C + log2(alpha[128] + alpha[127])), both on lane 63
    if (lane == 63) {
        float tail = fmaxf(d.a128 + d.a1, 1e-37f);
        out[b] = -LN2F * (d.C + flog2(tail));
    }
}

extern "C" void kernel_launch(void* const* d_in, const int* in_sizes, int n_in,
                              void* d_out, int out_size, void* d_ws, size_t ws_size,
                              hipStream_t stream) {
    const int*   y_true = (const int*)d_in[0];
    const float* y_pred = (const float*)d_in[1];
    float*       out    = (float*)d_out;
    ctc_kernel<<<dim3(BB), dim3(64), 0, stream>>>(y_true, y_pred, out);
}

// Round 5
// 196.165 us; speedup vs baseline: 1.0254x; 1.0254x over previous
//
#include <hip/hip_runtime.h>
#include <math.h>

// CTC batch cost (Keras ctc_batch_cost), gfx950. B=256,T=512,V=256,L=64,S=129.
//
// One block = one batch element = 2 waves (128 threads):
//   wave 1 (loader): streams blank + per-lane label probabilities for each
//     32-step chunk global -> compact LDS ring (4 buffers), 2 chunks ahead.
//     No dependency chain -> absorbs all HBM latency with deep MLP.
//   wave 0 (DP): per chunk reads 64 values from LDS into registers, then
//     runs 32 register-only DP steps. Never touches global y_pred.
// One __syncthreads per chunk synchronizes the ring.
//
// DP math (identical to R4, absmax 0.0 verified): scaled forward algorithm
// in linear space with per-lane power-of-two rescaling; lane L owns extended
// states 2L and 2L+1, lane 63 also owns s=128; cross-lane alpha[2L-1] via
// DPP wave_shr:1; phase A (t<128, frontier active) rescales every step,
// phase B every 8 steps. No transcendentals in the loop.

#define BB   256
#define TI   512
#define VV   256
#define LL   64
#define CH   32
#define NCH  (TI / CH)          // 16 chunks
#define EPSF 1e-7f
#define LN2F 0.6931471805599453f

#if __has_builtin(__builtin_amdgcn_logf)
__device__ __forceinline__ float flog2(float x) { return __builtin_amdgcn_logf(x); }
#else
__device__ __forceinline__ float flog2(float x) { return __log2f(x); }
#endif

template <int CTRL>
__device__ __forceinline__ float dppf(float oldv, float v) {
    return __int_as_float(__builtin_amdgcn_update_dpp(
        __float_as_int(oldv), __float_as_int(v), CTRL, 0xF, 0xF, false));
}
// lane i <- lane i-1; lane 0 <- 0.0f  (v_mov_b32_dpp wave_shr:1)
__device__ __forceinline__ float shup0(float x) { return dppf<0x138>(0.0f, x); }

struct DP {
    float a0, a1, a128;   // scaled alphas (a128 meaningful on lane 63)
    float C;              // log2 of this lane's scale (integer-valued float)
    float f, fs;          // 2^(C[l-1]-C[l]), and f*skip
    float skipf;
    int   lane;
};

__device__ __forceinline__ void rescale(DP& d) {
    float m  = fmaxf(fmaxf(d.a0, d.a1), d.a128);     // v_max3
    int   mi    = __float_as_int(m);                 // m >= 0
    int   ebits = mi & 0x7f800000;
    bool  dead  = (ebits == 0);                      // m < 2^-126 (0/denorm)
    float s = __int_as_float((254 << 23) - ebits);   // exact 2^-E
    s = dead ? 1.0f : s;
    d.a0 *= s; d.a1 *= s; d.a128 *= s;               // exact pow2 scaling
    float Ei  = (float)((mi >> 23) - 127);           // E (unused if dead)
    float Cm1 = shup0(d.C);                          // left C (pre-update)
    d.C = dead ? Cm1 : (d.C + Ei);                   // dead lanes adopt
    float Cm1b = shup0(d.C);                         // left C (post-update)
    int dCi = (int)(Cm1b - d.C);                     // exact integer
    int e = dCi + 127;
    e = e < 0 ? 0 : (e > 254 ? 254 : e);             // clamp: f=0 / f=2^127
    float fn = __int_as_float(e << 23);              // 2^dCi
    d.f  = (d.lane == 0) ? 0.0f : fn;                // alpha[-1] == 0
    d.fs = d.f * d.skipf;
}

__device__ __forceinline__ void dp_step(DP& d, float pb, float pl) {
    float pa1 = shup0(d.a1);                         // alpha[2L-1], prev scale
    float s01 = d.a0 + d.a1;
    float na0   = fmaf(pa1, d.f,  d.a0) * pb;        // (a0 + pa1*f)*pb
    float na1   = fmaf(pa1, d.fs, s01)  * pl;        // (a1+a0+skip*pa1*f)*pl
    float na128 = (d.a128 + d.a1) * pb;              // lane 63
    d.a0 = na0; d.a1 = na1; d.a128 = na128;
}

template <bool PA, bool FIRST>
__device__ __forceinline__ void dp_chunk(DP& d, const float (&pb)[CH],
                                         const float (&pl)[CH]) {
    #pragma unroll
    for (int tt = 0; tt < CH; ++tt) {
        if (FIRST && tt == 0) {
            d.a0 = (d.lane == 0) ? pb[0] : 0.0f;     // alpha0: s=0, s=1 only
            d.a1 = (d.lane == 0) ? pl[0] : 0.0f;
        } else {
            dp_step(d, pb[tt], pl[tt]);
        }
        if (PA || (tt & 7) == 7) rescale(d);
    }
}

// loader wave: fetch chunk cc's blank col + per-lane label cols -> LDS
__device__ __forceinline__ void fill_chunk(const float* __restrict__ src,
                                           int lab, int cc, int lane,
                                           float* __restrict__ pbuf,
                                           float* __restrict__ lbuf) {
    const float* rowbase = src + (size_t)cc * CH * VV;
    const int r = lane & 31;
    // blank col for the chunk's 32 rows (lanes 32..63 duplicate, same lines)
    float bv = rowbase[r * VV + (VV - 1)];
    // label gathers: one 64-lane gather per row
    float lv[CH];
    #pragma unroll
    for (int i = 0; i < CH; ++i)
        lv[i] = rowbase[i * VV + lab];
    if (lane < 32) pbuf[r] = bv + EPSF;
    #pragma unroll
    for (int i = 0; i < CH; ++i)
        lbuf[i * 64 + lane] = lv[i] + EPSF;
}

__global__ __launch_bounds__(128) void ctc_kernel(
        const int* __restrict__ y_true,
        const float* __restrict__ y_pred,
        float* __restrict__ out) {
    __shared__ float pbuf[4][CH];          // blank prob ring
    __shared__ float lbuf[4][CH * 64];     // label prob ring (32 KB)

    const int b    = blockIdx.x;
    const int tid  = threadIdx.x;
    const int lane = tid & 63;
    const int wave = tid >> 6;
    const float* src = y_pred + (size_t)b * TI * VV;

    const int lab = y_true[b * LL + lane];

    DP d;
    d.lane = lane;
    {
        const int prevLab = __shfl_up(lab, 1);
        d.skipf = (lane == 0 || lab != prevLab) ? 1.0f : 0.0f;
    }
    d.a0 = 0.0f; d.a1 = 0.0f; d.a128 = 0.0f;
    d.C = 0.0f; d.f = 0.0f; d.fs = 0.0f;

    // prologue: loader stages chunks 0 and 1
    if (wave == 1) {
        fill_chunk(src, lab, 0, lane, pbuf[0], lbuf[0]);
        fill_chunk(src, lab, 1, lane, pbuf[1], lbuf[1]);
    }
    __syncthreads();

    for (int c = 0; c < NCH; ++c) {
        if (wave == 1) {
            if (c + 2 < NCH)
                fill_chunk(src, lab, c + 2, lane,
                           pbuf[(c + 2) & 3], lbuf[(c + 2) & 3]);
        } else {
            // LDS -> registers for this chunk
            float pb[CH], pl[CH];
            const float* pp = pbuf[c & 3];
            const float* ll = lbuf[c & 3] + lane;
            #pragma unroll
            for (int i = 0; i < CH; ++i) {
                pb[i] = pp[i];             // broadcast read
                pl[i] = ll[i * 64];        // conflict-free (2-way)
            }
            if (c == 0)      dp_chunk<true,  true >(d, pb, pl);
            else if (c < 4)  dp_chunk<true,  false>(d, pb, pl);  // t<128
            else             dp_chunk<false, false>(d, pb, pl);
        }
        __syncthreads();
    }

    // loss = -ln2 * (C + log2(alpha[128] + alpha[127])), lane 63 of DP wave
    if (wave == 0 && lane == 63) {
        float tail = fmaxf(d.a128 + d.a1, 1e-37f);
        out[b] = -LN2F * (d.C + flog2(tail));
    }
}

extern "C" void kernel_launch(void* const* d_in, const int* in_sizes, int n_in,
                              void* d_out, int out_size, void* d_ws, size_t ws_size,
                              hipStream_t stream) {
    const int*   y_true = (const int*)d_in[0];
    const float* y_pred = (const float*)d_in[1];
    float*       out    = (float*)d_out;
    ctc_kernel<<<dim3(BB), dim3(128), 0, stream>>>(y_true, y_pred, out);
}